// Round 2
// baseline (317.778 us; speedup 1.0000x reference)
//
#include <hip/hip_runtime.h>

#define NPT   4096
#define KNN_K 16
#define EPSV  1e-5f

// ---- ws float layout ----
#define W0T_OFF 0                  // [67][64] folded (rows 0..63 = points cols, 64..66 = xyz cols)
#define B0_OFF  4288               // [64]
#define W1T_OFF 4352               // [64][64]  (ic-major)
#define B1_OFF  8448               // [64]
#define W2T_OFF 8512               // [64][128] (ic-major)
#define B2_OFF  16704              // [128]
#define IDX_OFF 16832              // int[4*4096*16]
#define XYZ4_OFF 278976            // float4[16384]
#define P_OFF   344512             // float[16384][64]  P = W0p*pts + W0x*xyz + b0
#define Q_OFF   1393088            // float[16384][64]  Q = W0x*xyz

typedef unsigned long long ull;

__global__ void prep_kernel(
    const float* __restrict__ xyz,
    const float* __restrict__ w0, const float* __restrict__ b0, const float* __restrict__ g0,
    const float* __restrict__ be0, const float* __restrict__ rm0, const float* __restrict__ rv0,
    const float* __restrict__ w1, const float* __restrict__ b1, const float* __restrict__ g1,
    const float* __restrict__ be1, const float* __restrict__ rm1, const float* __restrict__ rv1,
    const float* __restrict__ w2, const float* __restrict__ b2, const float* __restrict__ g2,
    const float* __restrict__ be2, const float* __restrict__ rm2, const float* __restrict__ rv2,
    float* __restrict__ ws) {
  int blk = blockIdx.x;
  if (blk < 64) {                        // xyz -> (x,y,z,sq), exact ref arithmetic for knn
    int i = blk * 256 + threadIdx.x;
    const float* p = xyz + i * 3;
    float x = p[0], y = p[1], z = p[2];
    float sq = __fadd_rn(__fadd_rn(__fmul_rn(x, x), __fmul_rn(y, y)), __fmul_rn(z, z));
    ((float4*)(ws + XYZ4_OFF))[i] = make_float4(x, y, z, sq);
    return;
  }
  int i = (blk - 64) * 256 + threadIdx.x;
  if (i < 4288) {                        // w0t: [ic'][oc]
    int oc = i & 63, icp = i >> 6;
    int col = (icp < 64) ? (icp + 3) : (icp - 64);
    float s = g0[oc] * rsqrtf(rv0[oc] + EPSV);
    ws[W0T_OFF + i] = w0[oc * 67 + col] * s;
  } else if (i < 4352) {
    int oc = i - 4288;
    float s = g0[oc] * rsqrtf(rv0[oc] + EPSV);
    ws[i] = (b0[oc] - rm0[oc]) * s + be0[oc];
  } else if (i < 8448) {
    int j = i - 4352; int oc = j & 63, ic = j >> 6;
    float s = g1[oc] * rsqrtf(rv1[oc] + EPSV);
    ws[i] = w1[oc * 64 + ic] * s;
  } else if (i < 8512) {
    int oc = i - 8448;
    float s = g1[oc] * rsqrtf(rv1[oc] + EPSV);
    ws[i] = (b1[oc] - rm1[oc]) * s + be1[oc];
  } else if (i < 16704) {
    int j = i - 8512; int ic = j >> 7, oc = j & 127;
    float s = g2[oc] * rsqrtf(rv2[oc] + EPSV);
    ws[i] = w2[oc * 64 + ic] * s;       // w2t [ic][oc]
  } else if (i < 16832) {
    int oc = i - 16704;
    float s = g2[oc] * rsqrtf(rv2[oc] + EPSV);
    ws[i] = (b2[oc] - rm2[oc]) * s + be2[oc];
  }
}

// P/Q precompute: wave = one point, lane = oc. w0t reads coalesced, points reads
// wave-uniform (scalarized). 70M MAC total.
__global__ __launch_bounds__(256) void pq_kernel(const float* __restrict__ xyz,
                                                 const float* __restrict__ points,
                                                 float* __restrict__ ws) {
  int tid = threadIdx.x;
  int oc = tid & 63;
  int i = blockIdx.x * 4 + (tid >> 6);
  const float* w0t = ws + W0T_OFF;
  float x = xyz[i * 3], y = xyz[i * 3 + 1], z = xyz[i * 3 + 2];
  float qacc = w0t[64 * 64 + oc] * x;
  qacc = fmaf(w0t[65 * 64 + oc], y, qacc);
  qacc = fmaf(w0t[66 * 64 + oc], z, qacc);
  float acc = ws[B0_OFF + oc] + qacc;
  const float* prow = points + (size_t)i * 64;
#pragma unroll 4
  for (int c = 0; c < 64; ++c) acc = fmaf(w0t[c * 64 + oc], prow[c], acc);
  ws[P_OFF + (size_t)i * 64 + oc] = acc;
  ws[Q_OFF + (size_t)i * 64 + oc] = qacc;
}

__device__ __forceinline__ ull minu64(ull a, ull b) { return a < b ? a : b; }
__device__ __forceinline__ ull maxu64(ull a, ull b) { return a > b ? a : b; }

__device__ __forceinline__ ull bitonic_sort64(ull v, int lane) {
#pragma unroll
  for (int k = 2; k <= 64; k <<= 1) {
#pragma unroll
    for (int j = k >> 1; j > 0; j >>= 1) {
      ull o = __shfl_xor(v, j);
      bool lower = (lane & j) == 0;
      bool up = (lane & k) == 0;
      v = (lower == up) ? minu64(v, o) : maxu64(v, o);
    }
  }
  return v;
}

__device__ __forceinline__ ull bitonic_merge64(ull v, int lane) {
#pragma unroll
  for (int j = 32; j > 0; j >>= 1) {
    ull o = __shfl_xor(v, j);
    v = ((lane & j) == 0) ? minu64(v, o) : maxu64(v, o);
  }
  return v;
}

// KNN (unchanged): wave/query threshold-filter + bitonic flush.
__global__ __launch_bounds__(256) void knn_kernel(const float4* __restrict__ cand4,
                                                  int* __restrict__ knnOut) {
  __shared__ __align__(16) float4 tile[1024];
  __shared__ ull buf[4][128];
  int tid = threadIdx.x;
  int lane = tid & 63, w = tid >> 6;
  int b = blockIdx.x >> 10;
  int n = ((blockIdx.x & 1023) << 2) + w;
  const float4* cb = cand4 + b * NPT;

  float4 q = cb[n];
  ull R = ~0ull;
  ull thresh = ~0ull;
  int cnt = 0;
  ull ltmask = (lane == 0) ? 0ull : (~0ull >> (64 - lane));

#pragma unroll 1
  for (int t = 0; t < 4; ++t) {
    __syncthreads();
#pragma unroll
    for (int j = 0; j < 4; ++j) tile[j * 256 + tid] = cb[t * 1024 + j * 256 + tid];
    __syncthreads();
#pragma unroll 1
    for (int i = 0; i < 16; ++i) {
      int ml = (i << 6) + lane;
      float4 c = tile[ml];
      float dot = __fadd_rn(__fadd_rn(__fmul_rn(q.x, c.x), __fmul_rn(q.y, c.y)),
                            __fmul_rn(q.z, c.z));
      float d2 = __fsub_rn(__fadd_rn(q.w, c.w), __fmul_rn(2.0f, dot));
      unsigned bits = __float_as_uint(d2);
      unsigned fk = bits ^ (0x80000000u | (unsigned)((int)bits >> 31));
      ull key = ((ull)fk << 32) | (unsigned)((t << 10) + ml);
      bool pred = key < thresh;
      ull mask = __ballot(pred);
      if (mask) {
        int pos = cnt + __popcll(mask & ltmask);
        if (pred) buf[w][pos] = key;
        cnt += __popcll(mask);
        if (cnt >= 64) {
          ull v = buf[w][lane];
          v = bitonic_sort64(v, lane);
          ull vr = __shfl(v, 63 - lane);
          R = minu64(R, vr);
          R = bitonic_merge64(R, lane);
          thresh = __shfl(R, 15);
          cnt -= 64;
          if (lane < cnt) {
            ull tmp = buf[w][64 + lane];
            buf[w][lane] = tmp;
          }
        }
      }
    }
  }
  {
    ull v = (lane < cnt) ? buf[w][lane] : ~0ull;
    v = bitonic_sort64(v, lane);
    ull vr = __shfl(v, 63 - lane);
    R = minu64(R, vr);
    R = bitonic_merge64(R, lane);
  }
  if (lane < KNN_K)
    knnOut[(b * NPT + n) * KNN_K + lane] = (int)(unsigned)(R & 0xFFFFFFFFull);
}

// 64 floats from a wave-uniform address into SGPRs via the scalar pipe.
// The compiler can't prove invariance of wbuf, so it would emit vector
// global_load for these (R1 post-mortem: 60% VMEM stall). Force s_load.
typedef __attribute__((ext_vector_type(16))) float f32x16;
__device__ __forceinline__ void sload64(const float* p, f32x16& a, f32x16& b,
                                        f32x16& c, f32x16& d) {
  asm("s_load_dwordx16 %0, %4, 0x0\n\t"
      "s_load_dwordx16 %1, %4, 0x40\n\t"
      "s_load_dwordx16 %2, %4, 0x80\n\t"
      "s_load_dwordx16 %3, %4, 0xc0\n\t"
      "s_waitcnt lgkmcnt(0)"
      : "=s"(a), "=s"(b), "=s"(c), "=s"(d)
      : "s"(p));
}

// MLP v4: lane = pair (wave = 4 queries x 16 k = 64 pairs). Activations in a
// per-wave LDS tile A[ic][pair] (conflict-free ds_read_b32, broadcast-reused
// 64x); weights via s_load_dwordx16 -> v_fmac_f32 vdst, s, v. Inner loop per
// ic: 1 ds_read + 4 s_load + 64 FMA. No __syncthreads, no bank conflicts.
__global__ __launch_bounds__(256) void mlp_kernel(
    const float* __restrict__ wbuf, const int* __restrict__ knn,
    float* __restrict__ out) {
  __shared__ float Ash[4][64 * 64];   // 64 KB: per-wave [ic][pair] tile
  int tid = threadIdx.x;
  int lane = tid & 63, w = tid >> 6;
  float* Aw = Ash[w];

  int q = blockIdx.x * 16 + w * 4 + (lane >> 4);   // flat query in [0, B*N)
  int k = lane & 15;
  int src = knn[q * KNN_K + k];                     // per-batch index
  int srow = (q & ~(NPT - 1)) + src;                // flat source row

  // ---- h0 = relu(P[src] - Q[q]) -> A[ic][pair] ----
  {
    const float4* Pp = (const float4*)(wbuf + P_OFF + (size_t)srow * 64);
    const float4* Qp = (const float4*)(wbuf + Q_OFF + (size_t)q * 64);
#pragma unroll
    for (int j = 0; j < 16; ++j) {
      float4 pv = Pp[j];
      float4 qv = Qp[j];
      int ic = j * 4;
      Aw[(ic + 0) * 64 + lane] = fmaxf(pv.x - qv.x, 0.0f);
      Aw[(ic + 1) * 64 + lane] = fmaxf(pv.y - qv.y, 0.0f);
      Aw[(ic + 2) * 64 + lane] = fmaxf(pv.z - qv.z, 0.0f);
      Aw[(ic + 3) * 64 + lane] = fmaxf(pv.w - qv.w, 0.0f);
    }
  }
  __builtin_amdgcn_wave_barrier();   // same-wave LDS RAW: in-order DS pipe

  // ---- layer 1: h1 = relu(W1 h0) ----
  float h1[64];
  {
    f32x16 ba, bb, bc, bd;
    sload64(wbuf + B1_OFF, ba, bb, bc, bd);
#pragma unroll
    for (int j = 0; j < 16; ++j) h1[j]      = ba[j];
#pragma unroll
    for (int j = 0; j < 16; ++j) h1[16 + j] = bb[j];
#pragma unroll
    for (int j = 0; j < 16; ++j) h1[32 + j] = bc[j];
#pragma unroll
    for (int j = 0; j < 16; ++j) h1[48 + j] = bd[j];
  }
  {
    const float* w1 = wbuf + W1T_OFF;
#pragma unroll 1
    for (int ic = 0; ic < 64; ++ic) {
      float a = Aw[ic * 64 + lane];            // ds_read_b32, 2-way (free)
      f32x16 wa, wb, wc, wd;
      sload64(w1 + ic * 64, wa, wb, wc, wd);   // scalar pipe, K$-resident
#pragma unroll
      for (int j = 0; j < 16; ++j) h1[j]      = fmaf(a, wa[j], h1[j]);
#pragma unroll
      for (int j = 0; j < 16; ++j) h1[16 + j] = fmaf(a, wb[j], h1[16 + j]);
#pragma unroll
      for (int j = 0; j < 16; ++j) h1[32 + j] = fmaf(a, wc[j], h1[32 + j]);
#pragma unroll
      for (int j = 0; j < 16; ++j) h1[48 + j] = fmaf(a, wd[j], h1[48 + j]);
    }
  }
  __builtin_amdgcn_wave_barrier();
#pragma unroll
  for (int j = 0; j < 64; ++j) Aw[j * 64 + lane] = fmaxf(h1[j], 0.0f);
  __builtin_amdgcn_wave_barrier();

  // ---- layer 2 (two 64-oc passes) + relu + max over k + store ----
  const float* w2 = wbuf + W2T_OFF;
  float* obase = out + (size_t)q * 128;
#pragma unroll 1
  for (int pass = 0; pass < 2; ++pass) {
    float acc[64];
    {
      f32x16 ba, bb, bc, bd;
      sload64(wbuf + B2_OFF + pass * 64, ba, bb, bc, bd);
#pragma unroll
      for (int j = 0; j < 16; ++j) acc[j]      = ba[j];
#pragma unroll
      for (int j = 0; j < 16; ++j) acc[16 + j] = bb[j];
#pragma unroll
      for (int j = 0; j < 16; ++j) acc[32 + j] = bc[j];
#pragma unroll
      for (int j = 0; j < 16; ++j) acc[48 + j] = bd[j];
    }
#pragma unroll 1
    for (int ic = 0; ic < 64; ++ic) {
      float a = Aw[ic * 64 + lane];
      f32x16 wa, wb, wc, wd;
      sload64(w2 + ic * 128 + pass * 64, wa, wb, wc, wd);
#pragma unroll
      for (int j = 0; j < 16; ++j) acc[j]      = fmaf(a, wa[j], acc[j]);
#pragma unroll
      for (int j = 0; j < 16; ++j) acc[16 + j] = fmaf(a, wb[j], acc[16 + j]);
#pragma unroll
      for (int j = 0; j < 16; ++j) acc[32 + j] = fmaf(a, wc[j], acc[32 + j]);
#pragma unroll
      for (int j = 0; j < 16; ++j) acc[48 + j] = fmaf(a, wd[j], acc[48 + j]);
    }
#pragma unroll
    for (int j = 0; j < 64; ++j) {
      float v = fmaxf(acc[j], 0.0f);
      v = fmaxf(v, __shfl_xor(v, 1));
      v = fmaxf(v, __shfl_xor(v, 2));
      v = fmaxf(v, __shfl_xor(v, 4));
      v = fmaxf(v, __shfl_xor(v, 8));
      acc[j] = v;
    }
    if (k == 0) {
      float4* o4 = (float4*)(obase + pass * 64);
#pragma unroll
      for (int j = 0; j < 16; ++j)
        o4[j] = make_float4(acc[4 * j], acc[4 * j + 1], acc[4 * j + 2], acc[4 * j + 3]);
    }
  }
}

extern "C" void kernel_launch(void* const* d_in, const int* in_sizes, int n_in,
                              void* d_out, int out_size, void* d_ws, size_t ws_size,
                              hipStream_t stream) {
  const float* xyz    = (const float*)d_in[0];
  const float* points = (const float*)d_in[1];
  float* wsF = (float*)d_ws;
  int* idxBuf = (int*)(wsF + IDX_OFF);
  const float4* cand4 = (const float4*)(wsF + XYZ4_OFF);

  prep_kernel<<<130, 256, 0, stream>>>(
      xyz,
      (const float*)d_in[2],  (const float*)d_in[3],  (const float*)d_in[4],
      (const float*)d_in[5],  (const float*)d_in[6],  (const float*)d_in[7],
      (const float*)d_in[8],  (const float*)d_in[9],  (const float*)d_in[10],
      (const float*)d_in[11], (const float*)d_in[12], (const float*)d_in[13],
      (const float*)d_in[14], (const float*)d_in[15], (const float*)d_in[16],
      (const float*)d_in[17], (const float*)d_in[18], (const float*)d_in[19],
      wsF);
  pq_kernel<<<4096, 256, 0, stream>>>(xyz, points, wsF);
  knn_kernel<<<4096, 256, 0, stream>>>(cand4, idxBuf);
  mlp_kernel<<<1024, 256, 0, stream>>>(wsF, idxBuf, (float*)d_out);
}

// Round 3
// 262.769 us; speedup vs baseline: 1.2093x; 1.2093x over previous
//
#include <hip/hip_runtime.h>

#define NPT   4096
#define KNN_K 16
#define EPSV  1e-5f

// ---- ws float layout ----
#define W0T_OFF 0                  // [67][64] folded (rows 0..63 = points cols, 64..66 = xyz cols)
#define B0_OFF  4288               // [64]
#define W1T_OFF 4352               // [64][64]  (ic-major)
#define B1_OFF  8448               // [64]
#define W2T_OFF 8512               // [64][128] (ic-major)
#define B2_OFF  16704              // [128]
#define IDX_OFF 16832              // int[4*4096*16]
#define XYZ4_OFF 278976            // float4[16384]
#define P_OFF   344512             // float[16384][64]  P = W0p*pts + W0x*xyz + b0
#define Q_OFF   1393088            // float[16384][64]  Q = W0x*xyz

typedef unsigned long long ull;

__global__ void prep_kernel(
    const float* __restrict__ xyz,
    const float* __restrict__ w0, const float* __restrict__ b0, const float* __restrict__ g0,
    const float* __restrict__ be0, const float* __restrict__ rm0, const float* __restrict__ rv0,
    const float* __restrict__ w1, const float* __restrict__ b1, const float* __restrict__ g1,
    const float* __restrict__ be1, const float* __restrict__ rm1, const float* __restrict__ rv1,
    const float* __restrict__ w2, const float* __restrict__ b2, const float* __restrict__ g2,
    const float* __restrict__ be2, const float* __restrict__ rm2, const float* __restrict__ rv2,
    float* __restrict__ ws) {
  int blk = blockIdx.x;
  if (blk < 64) {                        // xyz -> (x,y,z,sq), exact ref arithmetic for knn
    int i = blk * 256 + threadIdx.x;
    const float* p = xyz + i * 3;
    float x = p[0], y = p[1], z = p[2];
    float sq = __fadd_rn(__fadd_rn(__fmul_rn(x, x), __fmul_rn(y, y)), __fmul_rn(z, z));
    ((float4*)(ws + XYZ4_OFF))[i] = make_float4(x, y, z, sq);
    return;
  }
  int i = (blk - 64) * 256 + threadIdx.x;
  if (i < 4288) {                        // w0t: [ic'][oc]
    int oc = i & 63, icp = i >> 6;
    int col = (icp < 64) ? (icp + 3) : (icp - 64);
    float s = g0[oc] * rsqrtf(rv0[oc] + EPSV);
    ws[W0T_OFF + i] = w0[oc * 67 + col] * s;
  } else if (i < 4352) {
    int oc = i - 4288;
    float s = g0[oc] * rsqrtf(rv0[oc] + EPSV);
    ws[i] = (b0[oc] - rm0[oc]) * s + be0[oc];
  } else if (i < 8448) {
    int j = i - 4352; int oc = j & 63, ic = j >> 6;
    float s = g1[oc] * rsqrtf(rv1[oc] + EPSV);
    ws[i] = w1[oc * 64 + ic] * s;
  } else if (i < 8512) {
    int oc = i - 8448;
    float s = g1[oc] * rsqrtf(rv1[oc] + EPSV);
    ws[i] = (b1[oc] - rm1[oc]) * s + be1[oc];
  } else if (i < 16704) {
    int j = i - 8512; int ic = j >> 7, oc = j & 127;
    float s = g2[oc] * rsqrtf(rv2[oc] + EPSV);
    ws[i] = w2[oc * 64 + ic] * s;       // w2t [ic][oc]
  } else if (i < 16832) {
    int oc = i - 16704;
    float s = g2[oc] * rsqrtf(rv2[oc] + EPSV);
    ws[i] = (b2[oc] - rm2[oc]) * s + be2[oc];
  }
}

// P/Q precompute: wave = one point, lane = oc. w0t reads coalesced, points reads
// wave-uniform (scalarized). 70M MAC total.
__global__ __launch_bounds__(256) void pq_kernel(const float* __restrict__ xyz,
                                                 const float* __restrict__ points,
                                                 float* __restrict__ ws) {
  int tid = threadIdx.x;
  int oc = tid & 63;
  int i = blockIdx.x * 4 + (tid >> 6);
  const float* w0t = ws + W0T_OFF;
  float x = xyz[i * 3], y = xyz[i * 3 + 1], z = xyz[i * 3 + 2];
  float qacc = w0t[64 * 64 + oc] * x;
  qacc = fmaf(w0t[65 * 64 + oc], y, qacc);
  qacc = fmaf(w0t[66 * 64 + oc], z, qacc);
  float acc = ws[B0_OFF + oc] + qacc;
  const float* prow = points + (size_t)i * 64;
#pragma unroll 4
  for (int c = 0; c < 64; ++c) acc = fmaf(w0t[c * 64 + oc], prow[c], acc);
  ws[P_OFF + (size_t)i * 64 + oc] = acc;
  ws[Q_OFF + (size_t)i * 64 + oc] = qacc;
}

__device__ __forceinline__ ull minu64(ull a, ull b) { return a < b ? a : b; }
__device__ __forceinline__ ull maxu64(ull a, ull b) { return a > b ? a : b; }

__device__ __forceinline__ ull bitonic_sort64(ull v, int lane) {
#pragma unroll
  for (int k = 2; k <= 64; k <<= 1) {
#pragma unroll
    for (int j = k >> 1; j > 0; j >>= 1) {
      ull o = __shfl_xor(v, j);
      bool lower = (lane & j) == 0;
      bool up = (lane & k) == 0;
      v = (lower == up) ? minu64(v, o) : maxu64(v, o);
    }
  }
  return v;
}

__device__ __forceinline__ ull bitonic_merge64(ull v, int lane) {
#pragma unroll
  for (int j = 32; j > 0; j >>= 1) {
    ull o = __shfl_xor(v, j);
    v = ((lane & j) == 0) ? minu64(v, o) : maxu64(v, o);
  }
  return v;
}

// KNN (unchanged): wave/query threshold-filter + bitonic flush.
__global__ __launch_bounds__(256) void knn_kernel(const float4* __restrict__ cand4,
                                                  int* __restrict__ knnOut) {
  __shared__ __align__(16) float4 tile[1024];
  __shared__ ull buf[4][128];
  int tid = threadIdx.x;
  int lane = tid & 63, w = tid >> 6;
  int b = blockIdx.x >> 10;
  int n = ((blockIdx.x & 1023) << 2) + w;
  const float4* cb = cand4 + b * NPT;

  float4 q = cb[n];
  ull R = ~0ull;
  ull thresh = ~0ull;
  int cnt = 0;
  ull ltmask = (lane == 0) ? 0ull : (~0ull >> (64 - lane));

#pragma unroll 1
  for (int t = 0; t < 4; ++t) {
    __syncthreads();
#pragma unroll
    for (int j = 0; j < 4; ++j) tile[j * 256 + tid] = cb[t * 1024 + j * 256 + tid];
    __syncthreads();
#pragma unroll 1
    for (int i = 0; i < 16; ++i) {
      int ml = (i << 6) + lane;
      float4 c = tile[ml];
      float dot = __fadd_rn(__fadd_rn(__fmul_rn(q.x, c.x), __fmul_rn(q.y, c.y)),
                            __fmul_rn(q.z, c.z));
      float d2 = __fsub_rn(__fadd_rn(q.w, c.w), __fmul_rn(2.0f, dot));
      unsigned bits = __float_as_uint(d2);
      unsigned fk = bits ^ (0x80000000u | (unsigned)((int)bits >> 31));
      ull key = ((ull)fk << 32) | (unsigned)((t << 10) + ml);
      bool pred = key < thresh;
      ull mask = __ballot(pred);
      if (mask) {
        int pos = cnt + __popcll(mask & ltmask);
        if (pred) buf[w][pos] = key;
        cnt += __popcll(mask);
        if (cnt >= 64) {
          ull v = buf[w][lane];
          v = bitonic_sort64(v, lane);
          ull vr = __shfl(v, 63 - lane);
          R = minu64(R, vr);
          R = bitonic_merge64(R, lane);
          thresh = __shfl(R, 15);
          cnt -= 64;
          if (lane < cnt) {
            ull tmp = buf[w][64 + lane];
            buf[w][lane] = tmp;
          }
        }
      }
    }
  }
  {
    ull v = (lane < cnt) ? buf[w][lane] : ~0ull;
    v = bitonic_sort64(v, lane);
    ull vr = __shfl(v, 63 - lane);
    R = minu64(R, vr);
    R = bitonic_merge64(R, lane);
  }
  if (lane < KNN_K)
    knnOut[(b * NPT + n) * KNN_K + lane] = (int)(unsigned)(R & 0xFFFFFFFFull);
}

// MLP v5: block = 256 thr (4 waves) = 16 queries = 256 pairs. Thread tile
// 8 pairs x 8 oc (64 acc) for ALL GEMM phases -> 4 ds_read_b128 per 64 FMA
// (0.25 LDS-floats/FMA, 1.5x less DS than v2), every read 8-way broadcast,
// conflict-free. LDS: A[64][256] (h0 then h1 in place) + 16 KB W-buffer
// staged W1 -> W2lo -> W2hi with register preloads (T14) hiding the global
// latency under the previous GEMM phase. 80 KB -> 2 blocks/CU.
__global__ __launch_bounds__(256) void mlp_kernel(
    const float* __restrict__ wbuf, const int* __restrict__ knn,
    float* __restrict__ out) {
  __shared__ __align__(16) float Ash[64 * 256];   // 64 KB [ic][p]
  __shared__ __align__(16) float Wsh[64 * 64];    // 16 KB [ic][oc]
  int tid = threadIdx.x;
  int qblk = blockIdx.x << 4;                     // 16 flat queries per block

  // ---- issue W1 preload (consumed after h0) ----
  const float4* w1g = (const float4*)(wbuf + W1T_OFF);
  float4 st0 = w1g[tid];
  float4 st1 = w1g[256 + tid];
  float4 st2 = w1g[512 + tid];
  float4 st3 = w1g[768 + tid];

  // ---- h0: one pair per thread ----
  {
    int p = tid;
    int q = qblk + (p >> 4);
    int k = p & 15;
    int src = knn[q * KNN_K + k];                 // coalesced: qblk*16 + tid
    int srow = (q & ~(NPT - 1)) + src;
    const float4* Pp = (const float4*)(wbuf + P_OFF + (size_t)srow * 64);
    const float4* Qp = (const float4*)(wbuf + Q_OFF + (size_t)q * 64);
#pragma unroll
    for (int j = 0; j < 16; ++j) {
      float4 pv = Pp[j];
      float4 qv = Qp[j];
      int ic = j * 4;
      Ash[(ic + 0) * 256 + p] = fmaxf(pv.x - qv.x, 0.0f);
      Ash[(ic + 1) * 256 + p] = fmaxf(pv.y - qv.y, 0.0f);
      Ash[(ic + 2) * 256 + p] = fmaxf(pv.z - qv.z, 0.0f);
      Ash[(ic + 3) * 256 + p] = fmaxf(pv.w - qv.w, 0.0f);
    }
  }
  // write W1 to LDS
  {
    float4* wl = (float4*)Wsh;
    wl[tid] = st0; wl[256 + tid] = st1; wl[512 + tid] = st2; wl[768 + tid] = st3;
  }
  // issue W2-lo preload (cols 0..63), in flight across L1
  const float4* w2g = (const float4*)(wbuf + W2T_OFF);   // [64][32 float4]
  {
    int r0 = tid, r1 = 256 + tid, r2 = 512 + tid, r3 = 768 + tid;
    st0 = w2g[(r0 >> 4) * 32 + (r0 & 15)];
    st1 = w2g[(r1 >> 4) * 32 + (r1 & 15)];
    st2 = w2g[(r2 >> 4) * 32 + (r2 & 15)];
    st3 = w2g[(r3 >> 4) * 32 + (r3 & 15)];
  }
  __syncthreads();

  int og = tid & 7, pg = tid >> 3;                // 32 pgrp x 8 ogrp
  const float* Arow = Ash + 8 * pg;
  const float* Wrow = Wsh + 8 * og;
  float acc[8][8];                                // [pair][oc]

  // ---- layer 1 ----
  {
    float4 b0v = *(const float4*)(wbuf + B1_OFF + 8 * og);
    float4 b1v = *(const float4*)(wbuf + B1_OFF + 8 * og + 4);
    float bj[8] = {b0v.x, b0v.y, b0v.z, b0v.w, b1v.x, b1v.y, b1v.z, b1v.w};
#pragma unroll
    for (int i = 0; i < 8; ++i)
#pragma unroll
      for (int j = 0; j < 8; ++j) acc[i][j] = bj[j];
#pragma unroll 4
    for (int ic = 0; ic < 64; ++ic) {
      float4 a0 = *(const float4*)(Arow + ic * 256);
      float4 a1 = *(const float4*)(Arow + ic * 256 + 4);
      float4 w0 = *(const float4*)(Wrow + ic * 64);
      float4 w1v = *(const float4*)(Wrow + ic * 64 + 4);
      float av[8] = {a0.x, a0.y, a0.z, a0.w, a1.x, a1.y, a1.z, a1.w};
      float wv[8] = {w0.x, w0.y, w0.z, w0.w, w1v.x, w1v.y, w1v.z, w1v.w};
#pragma unroll
      for (int i = 0; i < 8; ++i)
#pragma unroll
        for (int j = 0; j < 8; ++j) acc[i][j] = fmaf(av[i], wv[j], acc[i][j]);
    }
  }
  __syncthreads();   // all h0 reads + W1 reads done
  // h1 -> A[oc][p] (8-way conflict on write, once per layer: accepted)
#pragma unroll
  for (int j = 0; j < 8; ++j) {
    int oc = 8 * og + j;
    *(float4*)(Ash + oc * 256 + 8 * pg) =
        make_float4(fmaxf(acc[0][j], 0.0f), fmaxf(acc[1][j], 0.0f),
                    fmaxf(acc[2][j], 0.0f), fmaxf(acc[3][j], 0.0f));
    *(float4*)(Ash + oc * 256 + 8 * pg + 4) =
        make_float4(fmaxf(acc[4][j], 0.0f), fmaxf(acc[5][j], 0.0f),
                    fmaxf(acc[6][j], 0.0f), fmaxf(acc[7][j], 0.0f));
  }
  // stage W2-lo from regs; issue W2-hi preload (in flight across pass 0)
  {
    float4* wl = (float4*)Wsh;
    wl[tid] = st0; wl[256 + tid] = st1; wl[512 + tid] = st2; wl[768 + tid] = st3;
    int r0 = tid, r1 = 256 + tid, r2 = 512 + tid, r3 = 768 + tid;
    st0 = w2g[(r0 >> 4) * 32 + 16 + (r0 & 15)];
    st1 = w2g[(r1 >> 4) * 32 + 16 + (r1 & 15)];
    st2 = w2g[(r2 >> 4) * 32 + 16 + (r2 & 15)];
    st3 = w2g[(r3 >> 4) * 32 + 16 + (r3 & 15)];
  }
  __syncthreads();

  // ---- layer 2, two passes of 64 oc ----
  int qout = qblk + (pg >> 1);
  float* obase = out + (size_t)qout * 128 + 8 * og;
#pragma unroll 1
  for (int pass = 0; pass < 2; ++pass) {
    {
      float4 b0v = *(const float4*)(wbuf + B2_OFF + pass * 64 + 8 * og);
      float4 b1v = *(const float4*)(wbuf + B2_OFF + pass * 64 + 8 * og + 4);
      float bj[8] = {b0v.x, b0v.y, b0v.z, b0v.w, b1v.x, b1v.y, b1v.z, b1v.w};
#pragma unroll
      for (int i = 0; i < 8; ++i)
#pragma unroll
        for (int j = 0; j < 8; ++j) acc[i][j] = bj[j];
    }
#pragma unroll 4
    for (int ic = 0; ic < 64; ++ic) {
      float4 a0 = *(const float4*)(Arow + ic * 256);
      float4 a1 = *(const float4*)(Arow + ic * 256 + 4);
      float4 w0 = *(const float4*)(Wrow + ic * 64);
      float4 w1v = *(const float4*)(Wrow + ic * 64 + 4);
      float av[8] = {a0.x, a0.y, a0.z, a0.w, a1.x, a1.y, a1.z, a1.w};
      float wv[8] = {w0.x, w0.y, w0.z, w0.w, w1v.x, w1v.y, w1v.z, w1v.w};
#pragma unroll
      for (int i = 0; i < 8; ++i)
#pragma unroll
        for (int j = 0; j < 8; ++j) acc[i][j] = fmaf(av[i], wv[j], acc[i][j]);
    }
    // relu + max over this thread's 8 pairs, then across pg^1 (other k-half)
    float m[8];
#pragma unroll
    for (int j = 0; j < 8; ++j) {
      float v = fmaxf(fmaxf(fmaxf(acc[0][j], acc[1][j]), fmaxf(acc[2][j], acc[3][j])),
                      fmaxf(fmaxf(acc[4][j], acc[5][j]), fmaxf(acc[6][j], acc[7][j])));
      v = fmaxf(v, 0.0f);
      m[j] = fmaxf(v, __shfl_xor(v, 8));   // pg<->pg^1 (lane bit 3)
    }
    if ((pg & 1) == 0) {
      *(float4*)(obase + pass * 64)     = make_float4(m[0], m[1], m[2], m[3]);
      *(float4*)(obase + pass * 64 + 4) = make_float4(m[4], m[5], m[6], m[7]);
    }
    if (pass == 0) {
      __syncthreads();   // pass-0 reads of Wsh done
      float4* wl = (float4*)Wsh;
      wl[tid] = st0; wl[256 + tid] = st1; wl[512 + tid] = st2; wl[768 + tid] = st3;
      __syncthreads();   // W2-hi visible
    }
  }
}

extern "C" void kernel_launch(void* const* d_in, const int* in_sizes, int n_in,
                              void* d_out, int out_size, void* d_ws, size_t ws_size,
                              hipStream_t stream) {
  const float* xyz    = (const float*)d_in[0];
  const float* points = (const float*)d_in[1];
  float* wsF = (float*)d_ws;
  int* idxBuf = (int*)(wsF + IDX_OFF);
  const float4* cand4 = (const float4*)(wsF + XYZ4_OFF);

  prep_kernel<<<130, 256, 0, stream>>>(
      xyz,
      (const float*)d_in[2],  (const float*)d_in[3],  (const float*)d_in[4],
      (const float*)d_in[5],  (const float*)d_in[6],  (const float*)d_in[7],
      (const float*)d_in[8],  (const float*)d_in[9],  (const float*)d_in[10],
      (const float*)d_in[11], (const float*)d_in[12], (const float*)d_in[13],
      (const float*)d_in[14], (const float*)d_in[15], (const float*)d_in[16],
      (const float*)d_in[17], (const float*)d_in[18], (const float*)d_in[19],
      wsF);
  pq_kernel<<<4096, 256, 0, stream>>>(xyz, points, wsF);
  knn_kernel<<<4096, 256, 0, stream>>>(cand4, idxBuf);
  mlp_kernel<<<1024, 256, 0, stream>>>(wsF, idxBuf, (float*)d_out);
}